// Round 11
// baseline (302.571 us; speedup 1.0000x reference)
//
#include <hip/hip_runtime.h>
#include <math.h>

typedef unsigned short u16;
typedef unsigned int u32;
typedef __attribute__((ext_vector_type(4))) u16 u16x4;
typedef __attribute__((ext_vector_type(8))) short bf16x8;
typedef __attribute__((ext_vector_type(4))) float f32x4;

#define MFMA16(a, b, c) __builtin_amdgcn_mfma_f32_16x16x32_bf16(a, b, c, 0, 0, 0)

namespace {
constexpr int BATCH = 8;
constexpr int CDIM  = 512;
constexpr int PD    = 256;
constexpr int NPIX  = 4096;
constexpr int NTOT  = PD * NPIX;
constexpr float LOG2E = 1.44269504088896f;

// fp32 workspace region (float offsets)
constexpr int OFF_PART = 0;       // 8*64*2
constexpr int OFF_STAT = 2048;    // 8*2
constexpr int OFF_L0   = 4096;    // 8*4096 partial L (m-half 0)
constexpr int OFF_L1   = 36864;   // 8*4096 partial L (m-half 1)

// bf16 regions (u16 offsets from ws base)
constexpr size_t U16_BASE = 139264;                      // byte 278528
constexpr size_t QT_ELEMS = (size_t)BATCH * NPIX * 16;   // 524288
constexpr size_t V_ELEMS  = (size_t)BATCH * PD * NPIX;   // 8388608
constexpr size_t Y_ELEMS  = (size_t)BATCH * NPIX * CDIM; // 16777216
constexpr size_t WP_ELEMS = (size_t)CDIM * CDIM;         // 262144
constexpr size_t WQ_ELEMS = 288 * 256;                   // 73728
constexpr size_t XN_ELEMS = (size_t)BATCH * NPIX * PD;   // 8388608
} // namespace

__device__ __forceinline__ u16 f2bf(float f) {
    union { float f; u32 u; } v; v.f = f;
    return (u16)((v.u + 0x7fffu + ((v.u >> 16) & 1u)) >> 16);
}
__device__ __forceinline__ float bf2f(u16 h) {
    union { u32 u; float f; } v; v.u = ((u32)h) << 16;
    return v.f;
}
__device__ __forceinline__ u32 cvtpk(float lo, float hi) {
    u32 r;
    asm("v_cvt_pk_bf16_f32 %0, %1, %2" : "=v"(r) : "v"(lo), "v"(hi));
    return r;
}

// ---------------- K1a: per-chunk partial sums for GroupNorm stats ----------
__global__ __launch_bounds__(256) void k_stats_partial(const float* __restrict__ x,
                                                       float* __restrict__ ws) {
    int b = blockIdx.y, chunk = blockIdx.x, t = threadIdx.x;
    const float4* x4 = reinterpret_cast<const float4*>(
        x + (size_t)b * CDIM * NPIX + (size_t)chunk * 16384);
    float s = 0.f, sq = 0.f;
#pragma unroll
    for (int i = 0; i < 16; ++i) {
        float4 v = x4[i * 256 + t];
        s  += v.x + v.y + v.z + v.w;
        sq += v.x * v.x + v.y * v.y + v.z * v.z + v.w * v.w;
    }
    for (int off = 32; off; off >>= 1) {
        s  += __shfl_down(s, off);
        sq += __shfl_down(sq, off);
    }
    __shared__ float red[8];
    int wid = t >> 6, lane = t & 63;
    if (lane == 0) { red[wid * 2] = s; red[wid * 2 + 1] = sq; }
    __syncthreads();
    if (t == 0) {
        float S = red[0] + red[2] + red[4] + red[6];
        float Q = red[1] + red[3] + red[5] + red[7];
        ws[OFF_PART + (b * 64 + chunk) * 2]     = S;
        ws[OFF_PART + (b * 64 + chunk) * 2 + 1] = Q;
    }
}

__global__ __launch_bounds__(64) void k_stats_final(float* __restrict__ ws) {
    int b = blockIdx.x, t = threadIdx.x;
    float s = ws[OFF_PART + (b * 64 + t) * 2];
    float q = ws[OFF_PART + (b * 64 + t) * 2 + 1];
    for (int off = 32; off; off >>= 1) {
        s += __shfl_down(s, off);
        q += __shfl_down(q, off);
    }
    if (t == 0) {
        float mean = s / (float)NTOT;
        float var  = q / (float)NTOT - mean * mean;
        ws[OFF_STAT + b * 2]     = mean;
        ws[OFF_STAT + b * 2 + 1] = rsqrtf(var + 1e-5f);
    }
}

// ---------------- merged fp32 -> bf16 convert (wproj then wqkv) ------------
__global__ __launch_bounds__(256) void k_cvt2(const float* __restrict__ wp,
                                              const float* __restrict__ wq,
                                              u16* __restrict__ wpb,
                                              u16* __restrict__ wqb) {
    int bx = blockIdx.x;
    const float* src = (bx < 256) ? wp : wq;
    u16* dst = (bx < 256) ? wpb : wqb;
    int base = (bx < 256) ? bx * 1024 : (bx - 256) * 1024;
    int i = base + threadIdx.x * 4;
    float4 v = *reinterpret_cast<const float4*>(src + i);
    u16x4 o;
    o.x = f2bf(v.x); o.y = f2bf(v.y); o.z = f2bf(v.z); o.w = f2bf(v.w);
    *reinterpret_cast<u16x4*>(dst + i) = o;
}

// ---------------- K2: prep = GroupNorm(x1)->xn  AND  silu(x2)->y[256:] -----
__global__ __launch_bounds__(256) void k_prep(const float* __restrict__ x,
        const float* __restrict__ gnw, const float* __restrict__ gnb,
        const float* __restrict__ wsf, u16* __restrict__ xn, u16* __restrict__ yb) {
    int b = blockIdx.z, yy = blockIdx.y, n0 = blockIdx.x * 64, t = threadIdx.x;
    __shared__ u16 T[64][72];
    int c = t >> 2, nb = (t & 3) * 16;
    if (yy < 4) {
        int ca = yy * 64 + c;
        float mu = wsf[OFF_STAT + b * 2], rs = wsf[OFF_STAT + b * 2 + 1];
        float a = rs * gnw[ca];
        float sh = gnb[ca] - mu * a;
        const float* xb = x + ((size_t)b * CDIM + ca) * NPIX;
#pragma unroll
        for (int j = 0; j < 4; ++j) {
            float4 v = *reinterpret_cast<const float4*>(xb + n0 + nb + j * 4);
            T[nb + j * 4 + 0][c] = f2bf(v.x * a + sh);
            T[nb + j * 4 + 1][c] = f2bf(v.y * a + sh);
            T[nb + j * 4 + 2][c] = f2bf(v.z * a + sh);
            T[nb + j * 4 + 3][c] = f2bf(v.w * a + sh);
        }
        __syncthreads();
        int n = t >> 2, cb = (t & 3) * 16;
        u16* dst = xn + ((size_t)b * NPIX + n0 + n) * PD + yy * 64 + cb;
#pragma unroll
        for (int j = 0; j < 4; ++j)
            *reinterpret_cast<u16x4*>(dst + j * 4) =
                *reinterpret_cast<u16x4*>(&T[n][cb + j * 4]);
    } else {
        int c0 = (yy - 4) * 64;
        const float* xb = x + ((size_t)b * CDIM + PD + c0 + c) * NPIX;
#pragma unroll
        for (int j = 0; j < 4; ++j) {
            float4 v = *reinterpret_cast<const float4*>(xb + n0 + nb + j * 4);
            T[nb + j * 4 + 0][c] = f2bf(v.x / (1.f + __expf(-v.x)));
            T[nb + j * 4 + 1][c] = f2bf(v.y / (1.f + __expf(-v.y)));
            T[nb + j * 4 + 2][c] = f2bf(v.z / (1.f + __expf(-v.z)));
            T[nb + j * 4 + 3][c] = f2bf(v.w / (1.f + __expf(-v.w)));
        }
        __syncthreads();
        int n = t >> 2, cb = (t & 3) * 16;
        u16* dst = yb + ((size_t)b * NPIX + n0 + n) * CDIM + PD + c0 + cb;
#pragma unroll
        for (int j = 0; j < 4; ++j)
            *reinterpret_cast<u16x4*>(dst + j * 4) =
                *reinterpret_cast<u16x4*>(&T[n][cb + j * 4]);
    }
}

// ---------------- K3: qkv = w_qkv_bf16 @ xn (MFMA) -------------------------
__global__ __launch_bounds__(256) void k_qkv(const u16* __restrict__ xn,
        const u16* __restrict__ wq, const float* __restrict__ bqkv,
        u16* __restrict__ qt, u16* __restrict__ kt, u16* __restrict__ vb) {
    int b = blockIdx.z, o0 = blockIdx.y * 32, n0 = blockIdx.x * 256;
    int t = threadIdx.x, w = t >> 6, l = t & 63, lg = l >> 4, lr = l & 15;
    int nbase = n0 + w * 64;
    const u16* xnb = xn + (size_t)b * NPIX * PD;
    const f32x4 z4 = {0.f, 0.f, 0.f, 0.f};
    f32x4 acc[2][4];
#pragma unroll
    for (int i = 0; i < 2; ++i)
#pragma unroll
        for (int j = 0; j < 4; ++j) acc[i][j] = z4;

#pragma unroll
    for (int k0 = 0; k0 < PD; k0 += 32) {
        bf16x8 xf[4], wf[2];
#pragma unroll
        for (int nf = 0; nf < 4; ++nf)
            xf[nf] = *reinterpret_cast<const bf16x8*>(
                xnb + (size_t)(nbase + nf * 16 + lr) * PD + k0 + lg * 8);
#pragma unroll
        for (int of = 0; of < 2; ++of)
            wf[of] = *reinterpret_cast<const bf16x8*>(
                wq + (size_t)(o0 + of * 16 + lr) * PD + k0 + lg * 8);
#pragma unroll
        for (int of = 0; of < 2; ++of)
#pragma unroll
            for (int nf = 0; nf < 4; ++nf)
                acc[of][nf] = MFMA16(xf[nf], wf[of], acc[of][nf]);
    }

    if (o0 == 0) {
#pragma unroll
        for (int of = 0; of < 2; ++of) {
            int o = of * 16 + lr;
            float bias = bqkv[o];
            float sc = (of == 0) ? 0.25f * LOG2E : 1.0f;
            u16* dst = (of == 0) ? (qt + (size_t)b * NPIX * 16 + lr)
                                 : (kt + (size_t)b * NPIX * 16 + lr);
#pragma unroll
            for (int nf = 0; nf < 4; ++nf) {
#pragma unroll
                for (int r = 0; r < 4; ++r) {
                    int n = nbase + nf * 16 + 4 * lg + r;
                    dst[(size_t)n * 16] = f2bf((acc[of][nf][r] + bias) * sc);
                }
            }
        }
    } else {
        u16* vout = vb + (size_t)b * PD * NPIX;
#pragma unroll
        for (int of = 0; of < 2; ++of) {
            int c = o0 - 32 + of * 16 + lr;
            float bias = bqkv[32 + c];
#pragma unroll
            for (int nf = 0; nf < 4; ++nf) {
                u16x4 pw;
                pw.x = f2bf(acc[of][nf][0] + bias);
                pw.y = f2bf(acc[of][nf][1] + bias);
                pw.z = f2bf(acc[of][nf][2] + bias);
                pw.w = f2bf(acc[of][nf][3] + bias);
                *reinterpret_cast<u16x4*>(
                    vout + (size_t)c * NPIX + nbase + nf * 16 + 4 * lg) = pw;
            }
        }
    }
}

// ---------------- K4: fused flash PV, 2-way m-split ------------------------
// r10 structure exactly, but grid 1024 = 8b x 64qt x 2 m-halves: each block
// runs 16 iters over its disjoint 2048-m range (identical per-iter phase work,
// no duplicated FLOPs or L2 traffic). Softmax-without-max is linear, so
// partial PV sums + partial L are combined by k_fin. 4 blocks/CU -> 4
// independent barrier domains hide each other's phase bubbles.
// Partials: half0 -> y[b][n][c<256] (bf16), half1 -> xn region (bf16, dead).
__global__ __launch_bounds__(512) void k_attn_pv(const u16* __restrict__ qt,
        const u16* __restrict__ kt, const u16* __restrict__ vb,
        u16* __restrict__ yb, u16* __restrict__ xnp, float* __restrict__ wsf) {
    int bid = blockIdx.x;
    int b = bid & 7, r2 = bid >> 3;
    int q0 = (r2 & 63) * 64, half = r2 >> 6;
    int t = threadIdx.x, w = t >> 6, l = t & 63, lg = l >> 4, lr = l & 15;
    int band = w & 3, mfb = w >> 2; // wave scores band `band`, mf in {mfb, mfb+2}
    __shared__ u16 Pl[16384];      // flat: [buf 8192][half 4096][n*64+m swizzled]
    __shared__ float Ls[2][64];

    const u16* Qt = qt + ((size_t)b * NPIX + q0) * 16;

    const bf16x8 zf = {0, 0, 0, 0, 0, 0, 0, 0};
    bf16x8 qf = zf;
    if (lg < 2)
        qf = *reinterpret_cast<const bf16x8*>(Qt + (band * 16 + lr) * 16 + lg * 8);

    // hoisted pointers (stepped per iteration), offset by this block's m-half
    const u16* kp  = kt + (size_t)b * NPIX * 16
                       + (size_t)(half * 2048 + mfb * 16 + lr) * 16 + lg * 8;
    const u16* vp0 = vb + (size_t)b * PD * NPIX
                       + (size_t)(w * 32 + lr) * NPIX + half * 2048 + lg * 8;
    const u16* vp1 = vp0 + (size_t)16 * NPIX;

    float lp = 0.f;
    const f32x4 z4 = {0.f, 0.f, 0.f, 0.f};
    f32x4 acc[2][4];
#pragma unroll
    for (int cf = 0; cf < 2; ++cf)
#pragma unroll
        for (int nf = 0; nf < 4; ++nf) acc[cf][nf] = z4;

    int n = band * 16 + lr;
    int swz = (n & 7) << 3;
    int wrb = (n * 64 + mfb * 16 + 4 * lg) ^ swz; // f-variant: ^(i*32), +h*4096

    int bufo = 0;
    for (int it = 0; it < 16; ++it) {
        // ---- scores S^T = K·Q^T: 4 frags (2 halves x 2 mf) ----
#pragma unroll
        for (int f = 0; f < 4; ++f) {
            int h = f >> 1, i = f & 1;
            bf16x8 kf = zf;
            if (lg < 2)
                kf = *reinterpret_cast<const bf16x8*>(kp + h * 1024 + i * 512);
            f32x4 s = MFMA16(kf, qf, z4);
            // p = exp2(s); log2e*0.25 baked into q; s bounded ~±10, no guard needed
            float p0 = exp2f(s[0]);
            float p1 = exp2f(s[1]);
            float p2 = exp2f(s[2]);
            float p3 = exp2f(s[3]);
            lp += (p0 + p1) + (p2 + p3);
            uint2 pw;
            pw.x = cvtpk(p0, p1);
            pw.y = cvtpk(p2, p3);
            *reinterpret_cast<uint2*>(
                &Pl[bufo + h * 4096 + (wrb ^ (i * 32))]) = pw;
        }
        __syncthreads(); // P ready
        // ---- PV over 4 slices (h, ks): acc[c][n] += V[c][m] * P[n][m] ----
#pragma unroll
        for (int sl = 0; sl < 4; ++sl) {
            int h = sl >> 1, ks = sl & 1;
            bf16x8 vf0 = *reinterpret_cast<const bf16x8*>(vp0 + h * 64 + ks * 32);
            bf16x8 vf1 = *reinterpret_cast<const bf16x8*>(vp1 + h * 64 + ks * 32);
#pragma unroll
            for (int nf = 0; nf < 4; ++nf) {
                int nn = nf * 16 + lr;
                bf16x8 pf = *reinterpret_cast<const bf16x8*>(
                    &Pl[bufo + h * 4096 +
                        ((nn * 64 + ks * 32 + lg * 8) ^ ((nn & 7) << 3))]);
                acc[0][nf] = MFMA16(vf0, pf, acc[0][nf]);
                acc[1][nf] = MFMA16(vf1, pf, acc[1][nf]);
            }
        }
        kp += 2048; vp0 += 128; vp1 += 128;
        bufo ^= 8192;
    }
    // ---- partial L for this m-half ----
    lp += __shfl_xor(lp, 16);
    lp += __shfl_xor(lp, 32);
    if (l < 16) Ls[mfb][band * 16 + l] = lp;
    __syncthreads();
    float* plh = wsf + (half == 0 ? OFF_L0 : OFF_L1) + b * NPIX + q0;
    if (t < 64) plh[t] = Ls[0][t] + Ls[1][t];
    // ---- write raw bf16 partial sums (no /L, no silu) ----
    u16* dst0;
    size_t stride;
    if (half == 0) { dst0 = yb  + ((size_t)b * NPIX + q0) * CDIM; stride = CDIM; }
    else           { dst0 = xnp + ((size_t)b * NPIX + q0) * PD;   stride = PD; }
#pragma unroll
    for (int nf = 0; nf < 4; ++nf) {
#pragma unroll
        for (int cf = 0; cf < 2; ++cf) {
            u16x4 pw;
#pragma unroll
            for (int r = 0; r < 4; ++r) pw[r] = f2bf(acc[cf][nf][r]);
            *reinterpret_cast<u16x4*>(
                dst0 + (size_t)(nf * 16 + lr) * stride + w * 32 + cf * 16 + 4 * lg) = pw;
        }
    }
}

// ---------------- K5: combine m-halves: y[c<256] = silu((p0+p1)/(L0+L1)) ---
__global__ __launch_bounds__(256) void k_fin(const float* __restrict__ wsf,
        const u16* __restrict__ xnp, u16* __restrict__ yb) {
    int bid = blockIdx.x;
    int b = bid & 7, n0 = (bid >> 3) * 64;
    int t = threadIdx.x;
    __shared__ float inv[64];
    if (t < 64) {
        float L = wsf[OFF_L0 + b * NPIX + n0 + t] + wsf[OFF_L1 + b * NPIX + n0 + t];
        inv[t] = 1.f / L;
    }
    __syncthreads();
    int nl = t >> 2, cb = (t & 3) * 64;
    float iv = inv[nl];
    u16* yrow = yb + ((size_t)b * NPIX + n0 + nl) * CDIM + cb;
    const u16* xrow = xnp + ((size_t)b * NPIX + n0 + nl) * PD + cb;
#pragma unroll
    for (int j = 0; j < 16; ++j) {
        u16x4 a = *reinterpret_cast<const u16x4*>(yrow + j * 4);
        u16x4 p = *reinterpret_cast<const u16x4*>(xrow + j * 4);
        u16x4 o;
#pragma unroll
        for (int r = 0; r < 4; ++r) {
            float v = (bf2f(a[r]) + bf2f(p[r])) * iv;
            o[r] = f2bf(v / (1.f + __expf(-v)));
        }
        *reinterpret_cast<u16x4*>(yrow + j * 4) = o;
    }
}

// ---------------- K6: out = w_proj_bf16 @ y_bf16 + b_proj (MFMA) -----------
__global__ __launch_bounds__(256) void k_proj_mfma(const u16* __restrict__ wb,
        const u16* __restrict__ yb, const float* __restrict__ bproj,
        float* __restrict__ out) {
    int b = blockIdx.z, n0 = blockIdx.x * 128, o0 = blockIdx.y * 128;
    int t = threadIdx.x, w = t >> 6, l = t & 63, lg = l >> 4, lr = l & 15;
    int wo = w & 1, wn = w >> 1;
    int obase = o0 + wo * 64, nbase = n0 + wn * 64;
    const u16* ybb = yb + (size_t)b * NPIX * CDIM;
    const f32x4 z4 = {0.f, 0.f, 0.f, 0.f};
    f32x4 acc[4][4];
#pragma unroll
    for (int i = 0; i < 4; ++i)
#pragma unroll
        for (int j = 0; j < 4; ++j) acc[i][j] = z4;

    for (int k0 = 0; k0 < CDIM; k0 += 32) {
        bf16x8 af[4], bfr[4];
#pragma unroll
        for (int of = 0; of < 4; ++of)
            af[of] = *reinterpret_cast<const bf16x8*>(
                wb + (size_t)(obase + of * 16 + lr) * CDIM + k0 + lg * 8);
#pragma unroll
        for (int nf = 0; nf < 4; ++nf)
            bfr[nf] = *reinterpret_cast<const bf16x8*>(
                ybb + (size_t)(nbase + nf * 16 + lr) * CDIM + k0 + lg * 8);
#pragma unroll
        for (int of = 0; of < 4; ++of)
#pragma unroll
            for (int nf = 0; nf < 4; ++nf)
                acc[of][nf] = MFMA16(af[of], bfr[nf], acc[of][nf]);
    }
#pragma unroll
    for (int of = 0; of < 4; ++of) {
        int o = obase + of * 16 + 4 * lg;
#pragma unroll
        for (int r = 0; r < 4; ++r) {
            float bb = bproj[o + r];
#pragma unroll
            for (int nf = 0; nf < 4; ++nf)
                out[((size_t)b * CDIM + o + r) * NPIX + nbase + nf * 16 + lr] =
                    acc[of][nf][r] + bb;
        }
    }
}

extern "C" void kernel_launch(void* const* d_in, const int* in_sizes, int n_in,
                              void* d_out, int out_size, void* d_ws, size_t ws_size,
                              hipStream_t stream) {
    const float* x     = (const float*)d_in[0];
    const float* gnw   = (const float*)d_in[1];
    const float* gnb   = (const float*)d_in[2];
    const float* wqkv  = (const float*)d_in[3];
    const float* bqkv  = (const float*)d_in[4];
    const float* wproj = (const float*)d_in[5];
    const float* bproj = (const float*)d_in[6];
    float* out = (float*)d_out;
    float* wsf = (float*)d_ws;

    u16* qtp = (u16*)d_ws + U16_BASE;
    u16* ktp = qtp + QT_ELEMS;
    u16* vbp = ktp + QT_ELEMS;
    u16* ybp = vbp + V_ELEMS;
    u16* wbp = ybp + Y_ELEMS;
    u16* wqb = wbp + WP_ELEMS;
    u16* xnp = wqb + WQ_ELEMS; // xn: qkv input, then reused for PV half-1 partials

    k_stats_partial<<<dim3(64, 8), 256, 0, stream>>>(x, wsf);
    k_stats_final<<<8, 64, 0, stream>>>(wsf);
    k_cvt2<<<328, 256, 0, stream>>>(wproj, wqkv, wbp, wqb);
    k_prep<<<dim3(64, 8, 8), 256, 0, stream>>>(x, gnw, gnb, wsf, xnp, ybp);
    k_qkv<<<dim3(16, 9, 8), 256, 0, stream>>>(xnp, wqb, bqkv, qtp, ktp, vbp);
    k_attn_pv<<<1024, 512, 0, stream>>>(qtp, ktp, vbp, ybp, xnp, wsf);
    k_fin<<<512, 256, 0, stream>>>(wsf, xnp, ybp);
    k_proj_mfma<<<dim3(32, 4, 8), 256, 0, stream>>>(wbp, ybp, bproj, out);
}

// Round 12
// 228.052 us; speedup vs baseline: 1.3268x; 1.3268x over previous
//
#include <hip/hip_runtime.h>
#include <math.h>

typedef unsigned short u16;
typedef unsigned int u32;
typedef __attribute__((ext_vector_type(4))) u16 u16x4;
typedef __attribute__((ext_vector_type(8))) short bf16x8;
typedef __attribute__((ext_vector_type(4))) float f32x4;

#define MFMA16(a, b, c) __builtin_amdgcn_mfma_f32_16x16x32_bf16(a, b, c, 0, 0, 0)

namespace {
constexpr int BATCH = 8;
constexpr int CDIM  = 512;
constexpr int PD    = 256;
constexpr int NPIX  = 4096;
constexpr int NTOT  = PD * NPIX;
constexpr float LOG2E = 1.44269504088896f;

// fp32 workspace region (float offsets)
constexpr int OFF_PART = 0;       // 8*64*2
constexpr int OFF_STAT = 2048;    // 8*2

// bf16 regions (u16 offsets from ws base)
constexpr size_t U16_BASE = 139264;                      // byte 278528
constexpr size_t QT_ELEMS = (size_t)BATCH * NPIX * 16;   // 524288
constexpr size_t V_ELEMS  = (size_t)BATCH * PD * NPIX;   // 8388608
constexpr size_t Y_ELEMS  = (size_t)BATCH * NPIX * CDIM; // 16777216
constexpr size_t WP_ELEMS = (size_t)CDIM * CDIM;         // 262144
constexpr size_t WQ_ELEMS = 288 * 256;                   // 73728
} // namespace

__device__ __forceinline__ u16 f2bf(float f) {
    union { float f; u32 u; } v; v.f = f;
    return (u16)((v.u + 0x7fffu + ((v.u >> 16) & 1u)) >> 16);
}
__device__ __forceinline__ u32 cvtpk(float lo, float hi) {
    u32 r;
    asm("v_cvt_pk_bf16_f32 %0, %1, %2" : "=v"(r) : "v"(lo), "v"(hi));
    return r;
}

// ---------------- K1a: per-chunk partial sums for GroupNorm stats ----------
__global__ __launch_bounds__(256) void k_stats_partial(const float* __restrict__ x,
                                                       float* __restrict__ ws) {
    int b = blockIdx.y, chunk = blockIdx.x, t = threadIdx.x;
    const float4* x4 = reinterpret_cast<const float4*>(
        x + (size_t)b * CDIM * NPIX + (size_t)chunk * 16384);
    float s = 0.f, sq = 0.f;
#pragma unroll
    for (int i = 0; i < 16; ++i) {
        float4 v = x4[i * 256 + t];
        s  += v.x + v.y + v.z + v.w;
        sq += v.x * v.x + v.y * v.y + v.z * v.z + v.w * v.w;
    }
    for (int off = 32; off; off >>= 1) {
        s  += __shfl_down(s, off);
        sq += __shfl_down(sq, off);
    }
    __shared__ float red[8];
    int wid = t >> 6, lane = t & 63;
    if (lane == 0) { red[wid * 2] = s; red[wid * 2 + 1] = sq; }
    __syncthreads();
    if (t == 0) {
        float S = red[0] + red[2] + red[4] + red[6];
        float Q = red[1] + red[3] + red[5] + red[7];
        ws[OFF_PART + (b * 64 + chunk) * 2]     = S;
        ws[OFF_PART + (b * 64 + chunk) * 2 + 1] = Q;
    }
}

__global__ __launch_bounds__(64) void k_stats_final(float* __restrict__ ws) {
    int b = blockIdx.x, t = threadIdx.x;
    float s = ws[OFF_PART + (b * 64 + t) * 2];
    float q = ws[OFF_PART + (b * 64 + t) * 2 + 1];
    for (int off = 32; off; off >>= 1) {
        s += __shfl_down(s, off);
        q += __shfl_down(q, off);
    }
    if (t == 0) {
        float mean = s / (float)NTOT;
        float var  = q / (float)NTOT - mean * mean;
        ws[OFF_STAT + b * 2]     = mean;
        ws[OFF_STAT + b * 2 + 1] = rsqrtf(var + 1e-5f);
    }
}

// ---------------- merged fp32 -> bf16 convert (wproj then wqkv) ------------
__global__ __launch_bounds__(256) void k_cvt2(const float* __restrict__ wp,
                                              const float* __restrict__ wq,
                                              u16* __restrict__ wpb,
                                              u16* __restrict__ wqb) {
    int bx = blockIdx.x;
    const float* src = (bx < 256) ? wp : wq;
    u16* dst = (bx < 256) ? wpb : wqb;
    int base = (bx < 256) ? bx * 1024 : (bx - 256) * 1024;
    int i = base + threadIdx.x * 4;
    float4 v = *reinterpret_cast<const float4*>(src + i);
    u16x4 o;
    o.x = f2bf(v.x); o.y = f2bf(v.y); o.z = f2bf(v.z); o.w = f2bf(v.w);
    *reinterpret_cast<u16x4*>(dst + i) = o;
}

// ---------------- K2: prep = GroupNorm(x1)->xn  AND  silu(x2)->y[256:] -----
__global__ __launch_bounds__(256) void k_prep(const float* __restrict__ x,
        const float* __restrict__ gnw, const float* __restrict__ gnb,
        const float* __restrict__ wsf, u16* __restrict__ xn, u16* __restrict__ yb) {
    int b = blockIdx.z, yy = blockIdx.y, n0 = blockIdx.x * 64, t = threadIdx.x;
    __shared__ u16 T[64][72];
    int c = t >> 2, nb = (t & 3) * 16;
    if (yy < 4) {
        int ca = yy * 64 + c;
        float mu = wsf[OFF_STAT + b * 2], rs = wsf[OFF_STAT + b * 2 + 1];
        float a = rs * gnw[ca];
        float sh = gnb[ca] - mu * a;
        const float* xb = x + ((size_t)b * CDIM + ca) * NPIX;
#pragma unroll
        for (int j = 0; j < 4; ++j) {
            float4 v = *reinterpret_cast<const float4*>(xb + n0 + nb + j * 4);
            T[nb + j * 4 + 0][c] = f2bf(v.x * a + sh);
            T[nb + j * 4 + 1][c] = f2bf(v.y * a + sh);
            T[nb + j * 4 + 2][c] = f2bf(v.z * a + sh);
            T[nb + j * 4 + 3][c] = f2bf(v.w * a + sh);
        }
        __syncthreads();
        int n = t >> 2, cb = (t & 3) * 16;
        u16* dst = xn + ((size_t)b * NPIX + n0 + n) * PD + yy * 64 + cb;
#pragma unroll
        for (int j = 0; j < 4; ++j)
            *reinterpret_cast<u16x4*>(dst + j * 4) =
                *reinterpret_cast<u16x4*>(&T[n][cb + j * 4]);
    } else {
        int c0 = (yy - 4) * 64;
        const float* xb = x + ((size_t)b * CDIM + PD + c0 + c) * NPIX;
#pragma unroll
        for (int j = 0; j < 4; ++j) {
            float4 v = *reinterpret_cast<const float4*>(xb + n0 + nb + j * 4);
            T[nb + j * 4 + 0][c] = f2bf(v.x / (1.f + __expf(-v.x)));
            T[nb + j * 4 + 1][c] = f2bf(v.y / (1.f + __expf(-v.y)));
            T[nb + j * 4 + 2][c] = f2bf(v.z / (1.f + __expf(-v.z)));
            T[nb + j * 4 + 3][c] = f2bf(v.w / (1.f + __expf(-v.w)));
        }
        __syncthreads();
        int n = t >> 2, cb = (t & 3) * 16;
        u16* dst = yb + ((size_t)b * NPIX + n0 + n) * CDIM + PD + c0 + cb;
#pragma unroll
        for (int j = 0; j < 4; ++j)
            *reinterpret_cast<u16x4*>(dst + j * 4) =
                *reinterpret_cast<u16x4*>(&T[n][cb + j * 4]);
    }
}

// ---------------- K3: qkv = w_qkv_bf16 @ xn (MFMA) -------------------------
// V written in tiled layout [b][m/8][c][m&7]: PV loads become lane-contiguous
// and wave-coalesced (16x fewer L2 line touches); V writes here coalesce too.
__global__ __launch_bounds__(256) void k_qkv(const u16* __restrict__ xn,
        const u16* __restrict__ wq, const float* __restrict__ bqkv,
        u16* __restrict__ qt, u16* __restrict__ kt, u16* __restrict__ vb) {
    int b = blockIdx.z, o0 = blockIdx.y * 32, n0 = blockIdx.x * 256;
    int t = threadIdx.x, w = t >> 6, l = t & 63, lg = l >> 4, lr = l & 15;
    int nbase = n0 + w * 64;
    const u16* xnb = xn + (size_t)b * NPIX * PD;
    const f32x4 z4 = {0.f, 0.f, 0.f, 0.f};
    f32x4 acc[2][4];
#pragma unroll
    for (int i = 0; i < 2; ++i)
#pragma unroll
        for (int j = 0; j < 4; ++j) acc[i][j] = z4;

#pragma unroll
    for (int k0 = 0; k0 < PD; k0 += 32) {
        bf16x8 xf[4], wf[2];
#pragma unroll
        for (int nf = 0; nf < 4; ++nf)
            xf[nf] = *reinterpret_cast<const bf16x8*>(
                xnb + (size_t)(nbase + nf * 16 + lr) * PD + k0 + lg * 8);
#pragma unroll
        for (int of = 0; of < 2; ++of)
            wf[of] = *reinterpret_cast<const bf16x8*>(
                wq + (size_t)(o0 + of * 16 + lr) * PD + k0 + lg * 8);
#pragma unroll
        for (int of = 0; of < 2; ++of)
#pragma unroll
            for (int nf = 0; nf < 4; ++nf)
                acc[of][nf] = MFMA16(xf[nf], wf[of], acc[of][nf]);
    }

    if (o0 == 0) {
#pragma unroll
        for (int of = 0; of < 2; ++of) {
            int o = of * 16 + lr;
            float bias = bqkv[o];
            float sc = (of == 0) ? 0.25f * LOG2E : 1.0f;
            u16* dst = (of == 0) ? (qt + (size_t)b * NPIX * 16 + lr)
                                 : (kt + (size_t)b * NPIX * 16 + lr);
#pragma unroll
            for (int nf = 0; nf < 4; ++nf) {
#pragma unroll
                for (int r = 0; r < 4; ++r) {
                    int n = nbase + nf * 16 + 4 * lg + r;
                    dst[(size_t)n * 16] = f2bf((acc[of][nf][r] + bias) * sc);
                }
            }
        }
    } else {
        u16* vout = vb + (size_t)b * PD * NPIX;
#pragma unroll
        for (int of = 0; of < 2; ++of) {
            int c = o0 - 32 + of * 16 + lr;
            float bias = bqkv[32 + c];
#pragma unroll
            for (int nf = 0; nf < 4; ++nf) {
                u16x4 pw;
                pw.x = f2bf(acc[of][nf][0] + bias);
                pw.y = f2bf(acc[of][nf][1] + bias);
                pw.z = f2bf(acc[of][nf][2] + bias);
                pw.w = f2bf(acc[of][nf][3] + bias);
                // tiled: elem(c, n) at (n>>3)*2048 + c*8 + (n&7); n = nbase+nf*16+4lg+r
                int nblk = (nbase >> 3) + nf * 2 + (lg >> 1);
                *reinterpret_cast<u16x4*>(
                    vout + (size_t)nblk * 2048 + c * 8 + (lg & 1) * 4) = pw;
            }
        }
    }
}

// ---------------- K4: fused flash PV ---------------------------------------
// r10 structure exactly (grid 512, 8 waves, q-tile 64, 128 m/iter, 1 barrier,
// scores -> barrier -> PV, double-buffered P, hoisted pointers). Change:
// V reads use the tiled [m/8][c][8] layout -> per-lane-contiguous 16 B,
// consecutive lanes 16 B apart = fully-coalesced wave loads.
__global__ __launch_bounds__(512) void k_attn_pv(const u16* __restrict__ qt,
        const u16* __restrict__ kt, const u16* __restrict__ vb,
        u16* __restrict__ yb) {
    int bid = blockIdx.x;
    int b = bid & 7, q0 = (bid >> 3) * 64;
    int t = threadIdx.x, w = t >> 6, l = t & 63, lg = l >> 4, lr = l & 15;
    int band = w & 3, mfb = w >> 2; // wave scores band `band`, mf in {mfb, mfb+2}
    __shared__ u16 Pl[16384];      // flat: [buf 8192][half 4096][n*64+m swizzled]
    __shared__ float Ls[2][64];

    const u16* Qt = qt + ((size_t)b * NPIX + q0) * 16;

    const bf16x8 zf = {0, 0, 0, 0, 0, 0, 0, 0};
    bf16x8 qf = zf;
    if (lg < 2)
        qf = *reinterpret_cast<const bf16x8*>(Qt + (band * 16 + lr) * 16 + lg * 8);

    // hoisted pointers (stepped per iteration)
    const u16* kp  = kt + (size_t)b * NPIX * 16 + (size_t)(mfb * 16 + lr) * 16 + lg * 8;
    // V tiled: elem(c, m) at (m>>3)*2048 + c*8 + (m&7); lane reads m = .. + lg*8
    const u16* vp0 = vb + (size_t)b * PD * NPIX + lg * 2048 + (size_t)(w * 32 + lr) * 8;
    const u16* vp1 = vp0 + 128; // +16 c

    float lp = 0.f;
    const f32x4 z4 = {0.f, 0.f, 0.f, 0.f};
    f32x4 acc[2][4];
#pragma unroll
    for (int cf = 0; cf < 2; ++cf)
#pragma unroll
        for (int nf = 0; nf < 4; ++nf) acc[cf][nf] = z4;

    int n = band * 16 + lr;
    int swz = (n & 7) << 3;
    int wrb = (n * 64 + mfb * 16 + 4 * lg) ^ swz; // f-variant: ^(i*32), +h*4096

    int bufo = 0;
    for (int it = 0; it < 32; ++it) {
        // ---- scores S^T = K·Q^T: 4 frags (2 halves x 2 mf) ----
#pragma unroll
        for (int f = 0; f < 4; ++f) {
            int h = f >> 1, i = f & 1;
            bf16x8 kf = zf;
            if (lg < 2)
                kf = *reinterpret_cast<const bf16x8*>(kp + h * 1024 + i * 512);
            f32x4 s = MFMA16(kf, qf, z4);
            // p = exp2(s); log2e*0.25 baked into q; s bounded ~±10, no guard needed
            float p0 = exp2f(s[0]);
            float p1 = exp2f(s[1]);
            float p2 = exp2f(s[2]);
            float p3 = exp2f(s[3]);
            lp += (p0 + p1) + (p2 + p3);
            uint2 pw;
            pw.x = cvtpk(p0, p1);
            pw.y = cvtpk(p2, p3);
            *reinterpret_cast<uint2*>(
                &Pl[bufo + h * 4096 + (wrb ^ (i * 32))]) = pw;
        }
        __syncthreads(); // P ready
        // ---- PV over 4 slices (h, ks): acc[c][n] += V[c][m] * P[n][m] ----
#pragma unroll
        for (int sl = 0; sl < 4; ++sl) {
            int h = sl >> 1, ks = sl & 1;
            bf16x8 vf0 = *reinterpret_cast<const bf16x8*>(
                vp0 + (h * 8 + ks * 4) * 2048);
            bf16x8 vf1 = *reinterpret_cast<const bf16x8*>(
                vp1 + (h * 8 + ks * 4) * 2048);
#pragma unroll
            for (int nf = 0; nf < 4; ++nf) {
                int nn = nf * 16 + lr;
                bf16x8 pf = *reinterpret_cast<const bf16x8*>(
                    &Pl[bufo + h * 4096 +
                        ((nn * 64 + ks * 32 + lg * 8) ^ ((nn & 7) << 3))]);
                acc[0][nf] = MFMA16(vf0, pf, acc[0][nf]);
                acc[1][nf] = MFMA16(vf1, pf, acc[1][nf]);
            }
        }
        kp += 2048; vp0 += 32768; vp1 += 32768;
        bufo ^= 8192;
    }
    // ---- finalize L: lane partial covers its (lg, mf-pair) m-slices ----
    lp += __shfl_xor(lp, 16);
    lp += __shfl_xor(lp, 32);
    if (l < 16) Ls[mfb][band * 16 + l] = lp; // waves mfb=0/1 hold complementary mf
    __syncthreads();
    float invl[4];
#pragma unroll
    for (int nf = 0; nf < 4; ++nf)
        invl[nf] = 1.f / (Ls[0][nf * 16 + lr] + Ls[1][nf * 16 + lr]);
    // ---- epilogue: /L, SiLU, write y transposed [b][n][c] bf16 ----
    u16* yrow = yb + (size_t)b * NPIX * CDIM;
#pragma unroll
    for (int nf = 0; nf < 4; ++nf) {
        int nq = q0 + nf * 16 + lr;
#pragma unroll
        for (int cf = 0; cf < 2; ++cf) {
            u16x4 pw;
#pragma unroll
            for (int r = 0; r < 4; ++r) {
                float v = acc[cf][nf][r] * invl[nf];
                pw[r] = f2bf(v / (1.f + __expf(-v)));
            }
            *reinterpret_cast<u16x4*>(
                yrow + (size_t)nq * CDIM + w * 32 + cf * 16 + 4 * lg) = pw;
        }
    }
}

// ---------------- K6: out = w_proj_bf16 @ y_bf16 + b_proj (MFMA) -----------
__global__ __launch_bounds__(256) void k_proj_mfma(const u16* __restrict__ wb,
        const u16* __restrict__ yb, const float* __restrict__ bproj,
        float* __restrict__ out) {
    int b = blockIdx.z, n0 = blockIdx.x * 128, o0 = blockIdx.y * 128;
    int t = threadIdx.x, w = t >> 6, l = t & 63, lg = l >> 4, lr = l & 15;
    int wo = w & 1, wn = w >> 1;
    int obase = o0 + wo * 64, nbase = n0 + wn * 64;
    const u16* ybb = yb + (size_t)b * NPIX * CDIM;
    const f32x4 z4 = {0.f, 0.f, 0.f, 0.f};
    f32x4 acc[4][4];
#pragma unroll
    for (int i = 0; i < 4; ++i)
#pragma unroll
        for (int j = 0; j < 4; ++j) acc[i][j] = z4;

    for (int k0 = 0; k0 < CDIM; k0 += 32) {
        bf16x8 af[4], bfr[4];
#pragma unroll
        for (int of = 0; of < 4; ++of)
            af[of] = *reinterpret_cast<const bf16x8*>(
                wb + (size_t)(obase + of * 16 + lr) * CDIM + k0 + lg * 8);
#pragma unroll
        for (int nf = 0; nf < 4; ++nf)
            bfr[nf] = *reinterpret_cast<const bf16x8*>(
                ybb + (size_t)(nbase + nf * 16 + lr) * CDIM + k0 + lg * 8);
#pragma unroll
        for (int of = 0; of < 4; ++of)
#pragma unroll
            for (int nf = 0; nf < 4; ++nf)
                acc[of][nf] = MFMA16(af[of], bfr[nf], acc[of][nf]);
    }
#pragma unroll
    for (int of = 0; of < 4; ++of) {
        int o = obase + of * 16 + 4 * lg;
#pragma unroll
        for (int r = 0; r < 4; ++r) {
            float bb = bproj[o + r];
#pragma unroll
            for (int nf = 0; nf < 4; ++nf)
                out[((size_t)b * CDIM + o + r) * NPIX + nbase + nf * 16 + lr] =
                    acc[of][nf][r] + bb;
        }
    }
}

extern "C" void kernel_launch(void* const* d_in, const int* in_sizes, int n_in,
                              void* d_out, int out_size, void* d_ws, size_t ws_size,
                              hipStream_t stream) {
    const float* x     = (const float*)d_in[0];
    const float* gnw   = (const float*)d_in[1];
    const float* gnb   = (const float*)d_in[2];
    const float* wqkv  = (const float*)d_in[3];
    const float* bqkv  = (const float*)d_in[4];
    const float* wproj = (const float*)d_in[5];
    const float* bproj = (const float*)d_in[6];
    float* out = (float*)d_out;
    float* wsf = (float*)d_ws;

    u16* qtp = (u16*)d_ws + U16_BASE;
    u16* ktp = qtp + QT_ELEMS;
    u16* vbp = ktp + QT_ELEMS;
    u16* ybp = vbp + V_ELEMS;
    u16* wbp = ybp + Y_ELEMS;
    u16* wqb = wbp + WP_ELEMS;
    u16* xnp = wqb + WQ_ELEMS; // xn has its own region (no aliasing)

    k_stats_partial<<<dim3(64, 8), 256, 0, stream>>>(x, wsf);
    k_stats_final<<<8, 64, 0, stream>>>(wsf);
    k_cvt2<<<328, 256, 0, stream>>>(wproj, wqkv, wbp, wqb);
    k_prep<<<dim3(64, 8, 8), 256, 0, stream>>>(x, gnw, gnb, wsf, xnp, ybp);
    k_qkv<<<dim3(16, 9, 8), 256, 0, stream>>>(xnp, wqb, bqkv, qtp, ktp, vbp);
    k_attn_pv<<<512, 512, 0, stream>>>(qtp, ktp, vbp, ybp);
    k_proj_mfma<<<dim3(32, 4, 8), 256, 0, stream>>>(wbp, ybp, bproj, out);
}

// Round 13
// 186.990 us; speedup vs baseline: 1.6181x; 1.2196x over previous
//
#include <hip/hip_runtime.h>
#include <math.h>

typedef unsigned short u16;
typedef unsigned int u32;
typedef __attribute__((ext_vector_type(4))) u16 u16x4;
typedef __attribute__((ext_vector_type(8))) short bf16x8;
typedef __attribute__((ext_vector_type(4))) float f32x4;

#define MFMA16(a, b, c) __builtin_amdgcn_mfma_f32_16x16x32_bf16(a, b, c, 0, 0, 0)

namespace {
constexpr int BATCH = 8;
constexpr int CDIM  = 512;
constexpr int PD    = 256;
constexpr int NPIX  = 4096;
constexpr int NTOT  = PD * NPIX;
constexpr float LOG2E = 1.44269504088896f;

// fp32 workspace region (float offsets)
constexpr int OFF_PART = 0;       // 8*64*2
constexpr int OFF_STAT = 2048;    // 8*2

// bf16 regions (u16 offsets from ws base)
constexpr size_t U16_BASE = 139264;                      // byte 278528
constexpr size_t QT_ELEMS = (size_t)BATCH * NPIX * 16;   // 524288
constexpr size_t V_ELEMS  = (size_t)BATCH * PD * NPIX;   // 8388608
constexpr size_t Y_ELEMS  = (size_t)BATCH * NPIX * CDIM; // 16777216
constexpr size_t WP_ELEMS = (size_t)CDIM * CDIM;         // 262144
constexpr size_t WQ_ELEMS = 288 * 256;                   // 73728

// tiled layouts: addr(r, k) = (k>>3)*(R*8) + r*8 + (k&7)
// xn: R=NPIX, K=PD   -> kblk stride 32768
// y : R=NPIX, K=CDIM -> kblk stride 32768
// wb: R=CDIM, K=CDIM -> kblk stride 4096
// wq: R=288,  K=PD   -> kblk stride 2304
// v : R=PD,   K=NPIX -> kblk stride 2048 (proven r12)
} // namespace

__device__ __forceinline__ u16 f2bf(float f) {
    union { float f; u32 u; } v; v.f = f;
    return (u16)((v.u + 0x7fffu + ((v.u >> 16) & 1u)) >> 16);
}
__device__ __forceinline__ u32 cvtpk(float lo, float hi) {
    u32 r;
    asm("v_cvt_pk_bf16_f32 %0, %1, %2" : "=v"(r) : "v"(lo), "v"(hi));
    return r;
}

// ---------------- K1a: per-chunk partial sums for GroupNorm stats ----------
__global__ __launch_bounds__(256) void k_stats_partial(const float* __restrict__ x,
                                                       float* __restrict__ ws) {
    int b = blockIdx.y, chunk = blockIdx.x, t = threadIdx.x;
    const float4* x4 = reinterpret_cast<const float4*>(
        x + (size_t)b * CDIM * NPIX + (size_t)chunk * 16384);
    float s = 0.f, sq = 0.f;
#pragma unroll
    for (int i = 0; i < 16; ++i) {
        float4 v = x4[i * 256 + t];
        s  += v.x + v.y + v.z + v.w;
        sq += v.x * v.x + v.y * v.y + v.z * v.z + v.w * v.w;
    }
    for (int off = 32; off; off >>= 1) {
        s  += __shfl_down(s, off);
        sq += __shfl_down(sq, off);
    }
    __shared__ float red[8];
    int wid = t >> 6, lane = t & 63;
    if (lane == 0) { red[wid * 2] = s; red[wid * 2 + 1] = sq; }
    __syncthreads();
    if (t == 0) {
        float S = red[0] + red[2] + red[4] + red[6];
        float Q = red[1] + red[3] + red[5] + red[7];
        ws[OFF_PART + (b * 64 + chunk) * 2]     = S;
        ws[OFF_PART + (b * 64 + chunk) * 2 + 1] = Q;
    }
}

__global__ __launch_bounds__(64) void k_stats_final(float* __restrict__ ws) {
    int b = blockIdx.x, t = threadIdx.x;
    float s = ws[OFF_PART + (b * 64 + t) * 2];
    float q = ws[OFF_PART + (b * 64 + t) * 2 + 1];
    for (int off = 32; off; off >>= 1) {
        s += __shfl_down(s, off);
        q += __shfl_down(q, off);
    }
    if (t == 0) {
        float mean = s / (float)NTOT;
        float var  = q / (float)NTOT - mean * mean;
        ws[OFF_STAT + b * 2]     = mean;
        ws[OFF_STAT + b * 2 + 1] = rsqrtf(var + 1e-5f);
    }
}

// ------- merged fp32 -> bf16 convert into TILED layouts (wproj, wqkv) ------
__global__ __launch_bounds__(256) void k_cvt2(const float* __restrict__ wp,
                                              const float* __restrict__ wq,
                                              u16* __restrict__ wpb,
                                              u16* __restrict__ wqb) {
    int bx = blockIdx.x, t = threadIdx.x;
    if (bx < 256) {
        int i = bx * 1024 + t * 4;        // linear over [512][512]
        int o = i >> 9, k = i & 511;
        float4 v = *reinterpret_cast<const float4*>(wp + i);
        u16x4 out;
        out.x = f2bf(v.x); out.y = f2bf(v.y); out.z = f2bf(v.z); out.w = f2bf(v.w);
        *reinterpret_cast<u16x4*>(wpb + (k >> 3) * 4096 + o * 8 + (k & 7)) = out;
    } else {
        int i = (bx - 256) * 1024 + t * 4; // linear over [288][256]
        int o = i >> 8, k = i & 255;
        float4 v = *reinterpret_cast<const float4*>(wq + i);
        u16x4 out;
        out.x = f2bf(v.x); out.y = f2bf(v.y); out.z = f2bf(v.z); out.w = f2bf(v.w);
        *reinterpret_cast<u16x4*>(wqb + (k >> 3) * 2304 + o * 8 + (k & 7)) = out;
    }
}

// ------- K2: prep = GroupNorm(x1)->xn(tiled)  AND  silu(x2)->y(tiled) ------
__global__ __launch_bounds__(256) void k_prep(const float* __restrict__ x,
        const float* __restrict__ gnw, const float* __restrict__ gnb,
        const float* __restrict__ wsf, u16* __restrict__ xn, u16* __restrict__ yb) {
    int b = blockIdx.z, yy = blockIdx.y, n0 = blockIdx.x * 64, t = threadIdx.x;
    __shared__ u16 T[64][72];
    int c = t >> 2, nb = (t & 3) * 16;
    if (yy < 4) {
        int ca = yy * 64 + c;
        float mu = wsf[OFF_STAT + b * 2], rs = wsf[OFF_STAT + b * 2 + 1];
        float a = rs * gnw[ca];
        float sh = gnb[ca] - mu * a;
        const float* xb = x + ((size_t)b * CDIM + ca) * NPIX;
#pragma unroll
        for (int j = 0; j < 4; ++j) {
            float4 v = *reinterpret_cast<const float4*>(xb + n0 + nb + j * 4);
            T[nb + j * 4 + 0][c] = f2bf(v.x * a + sh);
            T[nb + j * 4 + 1][c] = f2bf(v.y * a + sh);
            T[nb + j * 4 + 2][c] = f2bf(v.z * a + sh);
            T[nb + j * 4 + 3][c] = f2bf(v.w * a + sh);
        }
        __syncthreads();
        int n = n0 + (t >> 2), cb = (t & 3) * 16;
        u16* dstb = xn + (size_t)b * NPIX * PD;
#pragma unroll
        for (int j = 0; j < 4; ++j) {
            int cg = yy * 64 + cb + j * 4;
            *reinterpret_cast<u16x4*>(dstb + (size_t)(cg >> 3) * 32768 + n * 8 + (cg & 7)) =
                *reinterpret_cast<u16x4*>(&T[t >> 2][cb + j * 4]);
        }
    } else {
        int c0 = (yy - 4) * 64;
        const float* xb = x + ((size_t)b * CDIM + PD + c0 + c) * NPIX;
#pragma unroll
        for (int j = 0; j < 4; ++j) {
            float4 v = *reinterpret_cast<const float4*>(xb + n0 + nb + j * 4);
            T[nb + j * 4 + 0][c] = f2bf(v.x / (1.f + __expf(-v.x)));
            T[nb + j * 4 + 1][c] = f2bf(v.y / (1.f + __expf(-v.y)));
            T[nb + j * 4 + 2][c] = f2bf(v.z / (1.f + __expf(-v.z)));
            T[nb + j * 4 + 3][c] = f2bf(v.w / (1.f + __expf(-v.w)));
        }
        __syncthreads();
        int n = n0 + (t >> 2), cb = (t & 3) * 16;
        u16* dstb = yb + (size_t)b * NPIX * CDIM;
#pragma unroll
        for (int j = 0; j < 4; ++j) {
            int cg = PD + c0 + cb + j * 4;
            *reinterpret_cast<u16x4*>(dstb + (size_t)(cg >> 3) * 32768 + n * 8 + (cg & 7)) =
                *reinterpret_cast<u16x4*>(&T[t >> 2][cb + j * 4]);
        }
    }
}

// ---------------- K3: qkv = w_qkv_bf16 @ xn (MFMA, tiled reads) ------------
__global__ __launch_bounds__(256) void k_qkv(const u16* __restrict__ xn,
        const u16* __restrict__ wq, const float* __restrict__ bqkv,
        u16* __restrict__ qt, u16* __restrict__ kt, u16* __restrict__ vb) {
    int b = blockIdx.z, o0 = blockIdx.y * 32, n0 = blockIdx.x * 256;
    int t = threadIdx.x, w = t >> 6, l = t & 63, lg = l >> 4, lr = l & 15;
    int nbase = n0 + w * 64;
    const u16* xnb = xn + (size_t)b * NPIX * PD;
    const f32x4 z4 = {0.f, 0.f, 0.f, 0.f};
    f32x4 acc[2][4];
#pragma unroll
    for (int i = 0; i < 2; ++i)
#pragma unroll
        for (int j = 0; j < 4; ++j) acc[i][j] = z4;

#pragma unroll
    for (int k0 = 0; k0 < PD; k0 += 32) {
        bf16x8 xf[4], wf[2];
#pragma unroll
        for (int nf = 0; nf < 4; ++nf)
            xf[nf] = *reinterpret_cast<const bf16x8*>(
                xnb + (size_t)((k0 >> 3) + lg) * 32768 + (nbase + nf * 16 + lr) * 8);
#pragma unroll
        for (int of = 0; of < 2; ++of)
            wf[of] = *reinterpret_cast<const bf16x8*>(
                wq + (size_t)((k0 >> 3) + lg) * 2304 + (o0 + of * 16 + lr) * 8);
#pragma unroll
        for (int of = 0; of < 2; ++of)
#pragma unroll
            for (int nf = 0; nf < 4; ++nf)
                acc[of][nf] = MFMA16(xf[nf], wf[of], acc[of][nf]);
    }

    if (o0 == 0) {
#pragma unroll
        for (int of = 0; of < 2; ++of) {
            int o = of * 16 + lr;
            float bias = bqkv[o];
            float sc = (of == 0) ? 0.25f * LOG2E : 1.0f;
            u16* dst = (of == 0) ? (qt + (size_t)b * NPIX * 16 + lr)
                                 : (kt + (size_t)b * NPIX * 16 + lr);
#pragma unroll
            for (int nf = 0; nf < 4; ++nf) {
#pragma unroll
                for (int r = 0; r < 4; ++r) {
                    int n = nbase + nf * 16 + 4 * lg + r;
                    dst[(size_t)n * 16] = f2bf((acc[of][nf][r] + bias) * sc);
                }
            }
        }
    } else {
        u16* vout = vb + (size_t)b * PD * NPIX;
#pragma unroll
        for (int of = 0; of < 2; ++of) {
            int c = o0 - 32 + of * 16 + lr;
            float bias = bqkv[32 + c];
#pragma unroll
            for (int nf = 0; nf < 4; ++nf) {
                u16x4 pw;
                pw.x = f2bf(acc[of][nf][0] + bias);
                pw.y = f2bf(acc[of][nf][1] + bias);
                pw.z = f2bf(acc[of][nf][2] + bias);
                pw.w = f2bf(acc[of][nf][3] + bias);
                // v tiled: elem(c, n) at (n>>3)*2048 + c*8 + (n&7)
                int nblk = (nbase >> 3) + nf * 2 + (lg >> 1);
                *reinterpret_cast<u16x4*>(
                    vout + (size_t)nblk * 2048 + c * 8 + (lg & 1) * 4) = pw;
            }
        }
    }
}

// ---------------- K4: fused flash PV (r12 structure; tiled y epilogue) -----
__global__ __launch_bounds__(512) void k_attn_pv(const u16* __restrict__ qt,
        const u16* __restrict__ kt, const u16* __restrict__ vb,
        u16* __restrict__ yb) {
    int bid = blockIdx.x;
    int b = bid & 7, q0 = (bid >> 3) * 64;
    int t = threadIdx.x, w = t >> 6, l = t & 63, lg = l >> 4, lr = l & 15;
    int band = w & 3, mfb = w >> 2; // wave scores band `band`, mf in {mfb, mfb+2}
    __shared__ u16 Pl[16384];      // flat: [buf 8192][half 4096][n*64+m swizzled]
    __shared__ float Ls[2][64];

    const u16* Qt = qt + ((size_t)b * NPIX + q0) * 16;

    const bf16x8 zf = {0, 0, 0, 0, 0, 0, 0, 0};
    bf16x8 qf = zf;
    if (lg < 2)
        qf = *reinterpret_cast<const bf16x8*>(Qt + (band * 16 + lr) * 16 + lg * 8);

    // hoisted pointers (stepped per iteration)
    const u16* kp  = kt + (size_t)b * NPIX * 16 + (size_t)(mfb * 16 + lr) * 16 + lg * 8;
    // V tiled: elem(c, m) at (m>>3)*2048 + c*8 + (m&7); lane reads m = .. + lg*8
    const u16* vp0 = vb + (size_t)b * PD * NPIX + lg * 2048 + (size_t)(w * 32 + lr) * 8;
    const u16* vp1 = vp0 + 128; // +16 c

    float lp = 0.f;
    const f32x4 z4 = {0.f, 0.f, 0.f, 0.f};
    f32x4 acc[2][4];
#pragma unroll
    for (int cf = 0; cf < 2; ++cf)
#pragma unroll
        for (int nf = 0; nf < 4; ++nf) acc[cf][nf] = z4;

    int n = band * 16 + lr;
    int swz = (n & 7) << 3;
    int wrb = (n * 64 + mfb * 16 + 4 * lg) ^ swz; // f-variant: ^(i*32), +h*4096

    int bufo = 0;
    for (int it = 0; it < 32; ++it) {
        // ---- scores S^T = K·Q^T: 4 frags (2 halves x 2 mf) ----
#pragma unroll
        for (int f = 0; f < 4; ++f) {
            int h = f >> 1, i = f & 1;
            bf16x8 kf = zf;
            if (lg < 2)
                kf = *reinterpret_cast<const bf16x8*>(kp + h * 1024 + i * 512);
            f32x4 s = MFMA16(kf, qf, z4);
            float p0 = exp2f(s[0]);
            float p1 = exp2f(s[1]);
            float p2 = exp2f(s[2]);
            float p3 = exp2f(s[3]);
            lp += (p0 + p1) + (p2 + p3);
            uint2 pw;
            pw.x = cvtpk(p0, p1);
            pw.y = cvtpk(p2, p3);
            *reinterpret_cast<uint2*>(
                &Pl[bufo + h * 4096 + (wrb ^ (i * 32))]) = pw;
        }
        __syncthreads(); // P ready
        // ---- PV over 4 slices (h, ks): acc[c][n] += V[c][m] * P[n][m] ----
#pragma unroll
        for (int sl = 0; sl < 4; ++sl) {
            int h = sl >> 1, ks = sl & 1;
            bf16x8 vf0 = *reinterpret_cast<const bf16x8*>(
                vp0 + (h * 8 + ks * 4) * 2048);
            bf16x8 vf1 = *reinterpret_cast<const bf16x8*>(
                vp1 + (h * 8 + ks * 4) * 2048);
#pragma unroll
            for (int nf = 0; nf < 4; ++nf) {
                int nn = nf * 16 + lr;
                bf16x8 pf = *reinterpret_cast<const bf16x8*>(
                    &Pl[bufo + h * 4096 +
                        ((nn * 64 + ks * 32 + lg * 8) ^ ((nn & 7) << 3))]);
                acc[0][nf] = MFMA16(vf0, pf, acc[0][nf]);
                acc[1][nf] = MFMA16(vf1, pf, acc[1][nf]);
            }
        }
        kp += 2048; vp0 += 32768; vp1 += 32768;
        bufo ^= 8192;
    }
    // ---- finalize L: lane partial covers its (lg, mf-pair) m-slices ----
    lp += __shfl_xor(lp, 16);
    lp += __shfl_xor(lp, 32);
    if (l < 16) Ls[mfb][band * 16 + l] = lp; // waves mfb=0/1 hold complementary mf
    __syncthreads();
    float invl[4];
#pragma unroll
    for (int nf = 0; nf < 4; ++nf)
        invl[nf] = 1.f / (Ls[0][nf * 16 + lr] + Ls[1][nf * 16 + lr]);
    // ---- epilogue: /L, SiLU, write y TILED: (c>>3)*32768 + n*8 + (c&7) ----
    u16* ybase = yb + (size_t)b * NPIX * CDIM;
#pragma unroll
    for (int nf = 0; nf < 4; ++nf) {
        int nq = q0 + nf * 16 + lr;
#pragma unroll
        for (int cf = 0; cf < 2; ++cf) {
            int cg = w * 32 + cf * 16 + 4 * lg;
            u16x4 pw;
#pragma unroll
            for (int r = 0; r < 4; ++r) {
                float v = acc[cf][nf][r] * invl[nf];
                pw[r] = f2bf(v / (1.f + __expf(-v)));
            }
            *reinterpret_cast<u16x4*>(
                ybase + (size_t)(cg >> 3) * 32768 + nq * 8 + (cg & 7)) = pw;
        }
    }
}

// -------- K6: out = w_proj_bf16 @ y_bf16 + b_proj (MFMA, tiled reads) ------
__global__ __launch_bounds__(256) void k_proj_mfma(const u16* __restrict__ wb,
        const u16* __restrict__ yb, const float* __restrict__ bproj,
        float* __restrict__ out) {
    int b = blockIdx.z, n0 = blockIdx.x * 128, o0 = blockIdx.y * 128;
    int t = threadIdx.x, w = t >> 6, l = t & 63, lg = l >> 4, lr = l & 15;
    int wo = w & 1, wn = w >> 1;
    int obase = o0 + wo * 64, nbase = n0 + wn * 64;
    const u16* ybb = yb + (size_t)b * NPIX * CDIM;
    const f32x4 z4 = {0.f, 0.f, 0.f, 0.f};
    f32x4 acc[4][4];
#pragma unroll
    for (int i = 0; i < 4; ++i)
#pragma unroll
        for (int j = 0; j < 4; ++j) acc[i][j] = z4;

    for (int k0 = 0; k0 < CDIM; k0 += 32) {
        bf16x8 af[4], bfr[4];
#pragma unroll
        for (int of = 0; of < 4; ++of)
            af[of] = *reinterpret_cast<const bf16x8*>(
                wb + (size_t)((k0 >> 3) + lg) * 4096 + (obase + of * 16 + lr) * 8);
#pragma unroll
        for (int nf = 0; nf < 4; ++nf)
            bfr[nf] = *reinterpret_cast<const bf16x8*>(
                ybb + (size_t)((k0 >> 3) + lg) * 32768 + (nbase + nf * 16 + lr) * 8);
#pragma unroll
        for (int of = 0; of < 4; ++of)
#pragma unroll
            for (int nf = 0; nf < 4; ++nf)
                acc[of][nf] = MFMA16(af[of], bfr[nf], acc[of][nf]);
    }
#pragma unroll
    for (int of = 0; of < 4; ++of) {
        int o = obase + of * 16 + 4 * lg;
#pragma unroll
        for (int r = 0; r < 4; ++r) {
            float bb = bproj[o + r];
#pragma unroll
            for (int nf = 0; nf < 4; ++nf)
                out[((size_t)b * CDIM + o + r) * NPIX + nbase + nf * 16 + lr] =
                    acc[of][nf][r] + bb;
        }
    }
}

extern "C" void kernel_launch(void* const* d_in, const int* in_sizes, int n_in,
                              void* d_out, int out_size, void* d_ws, size_t ws_size,
                              hipStream_t stream) {
    const float* x     = (const float*)d_in[0];
    const float* gnw   = (const float*)d_in[1];
    const float* gnb   = (const float*)d_in[2];
    const float* wqkv  = (const float*)d_in[3];
    const float* bqkv  = (const float*)d_in[4];
    const float* wproj = (const float*)d_in[5];
    const float* bproj = (const float*)d_in[6];
    float* out = (float*)d_out;
    float* wsf = (float*)d_ws;

    u16* qtp = (u16*)d_ws + U16_BASE;
    u16* ktp = qtp + QT_ELEMS;
    u16* vbp = ktp + QT_ELEMS;
    u16* ybp = vbp + V_ELEMS;
    u16* wbp = ybp + Y_ELEMS;
    u16* wqb = wbp + WP_ELEMS;
    u16* xnp = wqb + WQ_ELEMS;

    k_stats_partial<<<dim3(64, 8), 256, 0, stream>>>(x, wsf);
    k_stats_final<<<8, 64, 0, stream>>>(wsf);
    k_cvt2<<<328, 256, 0, stream>>>(wproj, wqkv, wbp, wqb);
    k_prep<<<dim3(64, 8, 8), 256, 0, stream>>>(x, gnw, gnb, wsf, xnp, ybp);
    k_qkv<<<dim3(16, 9, 8), 256, 0, stream>>>(xnp, wqb, bqkv, qtp, ktp, vbp);
    k_attn_pv<<<512, 512, 0, stream>>>(qtp, ktp, vbp, ybp);
    k_proj_mfma<<<dim3(32, 4, 8), 256, 0, stream>>>(wbp, ybp, bproj, out);
}

// Round 15
// 184.128 us; speedup vs baseline: 1.6433x; 1.0155x over previous
//
#include <hip/hip_runtime.h>
#include <math.h>

typedef unsigned short u16;
typedef unsigned int u32;
typedef __attribute__((ext_vector_type(4))) u16 u16x4;
typedef __attribute__((ext_vector_type(8))) short bf16x8;
typedef __attribute__((ext_vector_type(4))) float f32x4;

#define MFMA16(a, b, c) __builtin_amdgcn_mfma_f32_16x16x32_bf16(a, b, c, 0, 0, 0)

namespace {
constexpr int BATCH = 8;
constexpr int CDIM  = 512;
constexpr int PD    = 256;
constexpr int NPIX  = 4096;
constexpr int NTOT  = PD * NPIX;
constexpr float LOG2E = 1.44269504088896f;

// fp32 workspace region (float offsets)
constexpr int OFF_PART = 0;       // 8*64*2
constexpr int OFF_STAT = 2048;    // 8*2

// bf16 regions (u16 offsets from ws base)
constexpr size_t U16_BASE = 139264;                      // byte 278528
constexpr size_t QT_ELEMS = (size_t)BATCH * NPIX * 16;   // 524288
constexpr size_t V_ELEMS  = (size_t)BATCH * PD * NPIX;   // 8388608
constexpr size_t Y_ELEMS  = (size_t)BATCH * NPIX * CDIM; // 16777216
constexpr size_t WP_ELEMS = (size_t)CDIM * CDIM;         // 262144
constexpr size_t WQ_ELEMS = 288 * 256;                   // 73728

// tiled layouts: addr(r, k) = (k>>3)*(R*8) + r*8 + (k&7)
// xn: R=NPIX, K=PD   -> kblk stride 32768
// y : R=NPIX, K=CDIM -> kblk stride 32768
// wb: R=CDIM, K=CDIM -> kblk stride 4096
// wq: R=288,  K=PD   -> kblk stride 2304
// v : R=PD,   K=NPIX -> kblk stride 2048
} // namespace

__device__ __forceinline__ u16 f2bf(float f) {
    union { float f; u32 u; } v; v.f = f;
    return (u16)((v.u + 0x7fffu + ((v.u >> 16) & 1u)) >> 16);
}
__device__ __forceinline__ u32 cvtpk(float lo, float hi) {
    u32 r;
    asm("v_cvt_pk_bf16_f32 %0, %1, %2" : "=v"(r) : "v"(lo), "v"(hi));
    return r;
}
// native 2^x via the intrinsic: emits a single v_exp_f32 WITH proper
// TRANS-pipe hazard handling (raw inline asm in r14 lacked the wait-states
// -> consumer read the result early -> NaN). libm exp2f would lower to a
// guarded multi-instruction sequence (the PV VALU bloat).
__device__ __forceinline__ float fexp2(float x) {
    return __builtin_amdgcn_exp2f(x);
}

// ---------------- K1a: per-chunk partial sums for GroupNorm stats ----------
__global__ __launch_bounds__(256) void k_stats_partial(const float* __restrict__ x,
                                                       float* __restrict__ ws) {
    int b = blockIdx.y, chunk = blockIdx.x, t = threadIdx.x;
    const float4* x4 = reinterpret_cast<const float4*>(
        x + (size_t)b * CDIM * NPIX + (size_t)chunk * 16384);
    float s = 0.f, sq = 0.f;
#pragma unroll
    for (int i = 0; i < 16; ++i) {
        float4 v = x4[i * 256 + t];
        s  += v.x + v.y + v.z + v.w;
        sq += v.x * v.x + v.y * v.y + v.z * v.z + v.w * v.w;
    }
    for (int off = 32; off; off >>= 1) {
        s  += __shfl_down(s, off);
        sq += __shfl_down(sq, off);
    }
    __shared__ float red[8];
    int wid = t >> 6, lane = t & 63;
    if (lane == 0) { red[wid * 2] = s; red[wid * 2 + 1] = sq; }
    __syncthreads();
    if (t == 0) {
        float S = red[0] + red[2] + red[4] + red[6];
        float Q = red[1] + red[3] + red[5] + red[7];
        ws[OFF_PART + (b * 64 + chunk) * 2]     = S;
        ws[OFF_PART + (b * 64 + chunk) * 2 + 1] = Q;
    }
}

__global__ __launch_bounds__(64) void k_stats_final(float* __restrict__ ws) {
    int b = blockIdx.x, t = threadIdx.x;
    float s = ws[OFF_PART + (b * 64 + t) * 2];
    float q = ws[OFF_PART + (b * 64 + t) * 2 + 1];
    for (int off = 32; off; off >>= 1) {
        s += __shfl_down(s, off);
        q += __shfl_down(q, off);
    }
    if (t == 0) {
        float mean = s / (float)NTOT;
        float var  = q / (float)NTOT - mean * mean;
        ws[OFF_STAT + b * 2]     = mean;
        ws[OFF_STAT + b * 2 + 1] = rsqrtf(var + 1e-5f);
    }
}

// ------- merged fp32 -> bf16 convert into TILED layouts (wproj, wqkv) ------
__global__ __launch_bounds__(256) void k_cvt2(const float* __restrict__ wp,
                                              const float* __restrict__ wq,
                                              u16* __restrict__ wpb,
                                              u16* __restrict__ wqb) {
    int bx = blockIdx.x, t = threadIdx.x;
    if (bx < 256) {
        int i = bx * 1024 + t * 4;        // linear over [512][512]
        int o = i >> 9, k = i & 511;
        float4 v = *reinterpret_cast<const float4*>(wp + i);
        u16x4 out;
        out.x = f2bf(v.x); out.y = f2bf(v.y); out.z = f2bf(v.z); out.w = f2bf(v.w);
        *reinterpret_cast<u16x4*>(wpb + (k >> 3) * 4096 + o * 8 + (k & 7)) = out;
    } else {
        int i = (bx - 256) * 1024 + t * 4; // linear over [288][256]
        int o = i >> 8, k = i & 255;
        float4 v = *reinterpret_cast<const float4*>(wq + i);
        u16x4 out;
        out.x = f2bf(v.x); out.y = f2bf(v.y); out.z = f2bf(v.z); out.w = f2bf(v.w);
        *reinterpret_cast<u16x4*>(wqb + (k >> 3) * 2304 + o * 8 + (k & 7)) = out;
    }
}

// ------- K2: prep = GroupNorm(x1)->xn(tiled)  AND  silu(x2)->y(tiled) ------
__global__ __launch_bounds__(256) void k_prep(const float* __restrict__ x,
        const float* __restrict__ gnw, const float* __restrict__ gnb,
        const float* __restrict__ wsf, u16* __restrict__ xn, u16* __restrict__ yb) {
    int b = blockIdx.z, yy = blockIdx.y, n0 = blockIdx.x * 64, t = threadIdx.x;
    __shared__ u16 T[64][72];
    int c = t >> 2, nb = (t & 3) * 16;
    if (yy < 4) {
        int ca = yy * 64 + c;
        float mu = wsf[OFF_STAT + b * 2], rs = wsf[OFF_STAT + b * 2 + 1];
        float a = rs * gnw[ca];
        float sh = gnb[ca] - mu * a;
        const float* xb = x + ((size_t)b * CDIM + ca) * NPIX;
#pragma unroll
        for (int j = 0; j < 4; ++j) {
            float4 v = *reinterpret_cast<const float4*>(xb + n0 + nb + j * 4);
            T[nb + j * 4 + 0][c] = f2bf(v.x * a + sh);
            T[nb + j * 4 + 1][c] = f2bf(v.y * a + sh);
            T[nb + j * 4 + 2][c] = f2bf(v.z * a + sh);
            T[nb + j * 4 + 3][c] = f2bf(v.w * a + sh);
        }
        __syncthreads();
        int n = n0 + (t >> 2), cb = (t & 3) * 16;
        u16* dstb = xn + (size_t)b * NPIX * PD;
#pragma unroll
        for (int j = 0; j < 4; ++j) {
            int cg = yy * 64 + cb + j * 4;
            *reinterpret_cast<u16x4*>(dstb + (size_t)(cg >> 3) * 32768 + n * 8 + (cg & 7)) =
                *reinterpret_cast<u16x4*>(&T[t >> 2][cb + j * 4]);
        }
    } else {
        int c0 = (yy - 4) * 64;
        const float* xb = x + ((size_t)b * CDIM + PD + c0 + c) * NPIX;
#pragma unroll
        for (int j = 0; j < 4; ++j) {
            float4 v = *reinterpret_cast<const float4*>(xb + n0 + nb + j * 4);
            T[nb + j * 4 + 0][c] = f2bf(v.x / (1.f + __expf(-v.x)));
            T[nb + j * 4 + 1][c] = f2bf(v.y / (1.f + __expf(-v.y)));
            T[nb + j * 4 + 2][c] = f2bf(v.z / (1.f + __expf(-v.z)));
            T[nb + j * 4 + 3][c] = f2bf(v.w / (1.f + __expf(-v.w)));
        }
        __syncthreads();
        int n = n0 + (t >> 2), cb = (t & 3) * 16;
        u16* dstb = yb + (size_t)b * NPIX * CDIM;
#pragma unroll
        for (int j = 0; j < 4; ++j) {
            int cg = PD + c0 + cb + j * 4;
            *reinterpret_cast<u16x4*>(dstb + (size_t)(cg >> 3) * 32768 + n * 8 + (cg & 7)) =
                *reinterpret_cast<u16x4*>(&T[t >> 2][cb + j * 4]);
        }
    }
}

// ---------------- K3: qkv = w_qkv_bf16 @ xn (MFMA, tiled reads) ------------
__global__ __launch_bounds__(256) void k_qkv(const u16* __restrict__ xn,
        const u16* __restrict__ wq, const float* __restrict__ bqkv,
        u16* __restrict__ qt, u16* __restrict__ kt, u16* __restrict__ vb) {
    int b = blockIdx.z, o0 = blockIdx.y * 32, n0 = blockIdx.x * 256;
    int t = threadIdx.x, w = t >> 6, l = t & 63, lg = l >> 4, lr = l & 15;
    int nbase = n0 + w * 64;
    const u16* xnb = xn + (size_t)b * NPIX * PD;
    const f32x4 z4 = {0.f, 0.f, 0.f, 0.f};
    f32x4 acc[2][4];
#pragma unroll
    for (int i = 0; i < 2; ++i)
#pragma unroll
        for (int j = 0; j < 4; ++j) acc[i][j] = z4;

#pragma unroll
    for (int k0 = 0; k0 < PD; k0 += 32) {
        bf16x8 xf[4], wf[2];
#pragma unroll
        for (int nf = 0; nf < 4; ++nf)
            xf[nf] = *reinterpret_cast<const bf16x8*>(
                xnb + (size_t)((k0 >> 3) + lg) * 32768 + (nbase + nf * 16 + lr) * 8);
#pragma unroll
        for (int of = 0; of < 2; ++of)
            wf[of] = *reinterpret_cast<const bf16x8*>(
                wq + (size_t)((k0 >> 3) + lg) * 2304 + (o0 + of * 16 + lr) * 8);
#pragma unroll
        for (int of = 0; of < 2; ++of)
#pragma unroll
            for (int nf = 0; nf < 4; ++nf)
                acc[of][nf] = MFMA16(xf[nf], wf[of], acc[of][nf]);
    }

    if (o0 == 0) {
#pragma unroll
        for (int of = 0; of < 2; ++of) {
            int o = of * 16 + lr;
            float bias = bqkv[o];
            float sc = (of == 0) ? 0.25f * LOG2E : 1.0f;
            u16* dst = (of == 0) ? (qt + (size_t)b * NPIX * 16 + lr)
                                 : (kt + (size_t)b * NPIX * 16 + lr);
#pragma unroll
            for (int nf = 0; nf < 4; ++nf) {
#pragma unroll
                for (int r = 0; r < 4; ++r) {
                    int n = nbase + nf * 16 + 4 * lg + r;
                    dst[(size_t)n * 16] = f2bf((acc[of][nf][r] + bias) * sc);
                }
            }
        }
    } else {
        u16* vout = vb + (size_t)b * PD * NPIX;
#pragma unroll
        for (int of = 0; of < 2; ++of) {
            int c = o0 - 32 + of * 16 + lr;
            float bias = bqkv[32 + c];
#pragma unroll
            for (int nf = 0; nf < 4; ++nf) {
                u16x4 pw;
                pw.x = f2bf(acc[of][nf][0] + bias);
                pw.y = f2bf(acc[of][nf][1] + bias);
                pw.z = f2bf(acc[of][nf][2] + bias);
                pw.w = f2bf(acc[of][nf][3] + bias);
                // v tiled: elem(c, n) at (n>>3)*2048 + c*8 + (n&7)
                int nblk = (nbase >> 3) + nf * 2 + (lg >> 1);
                *reinterpret_cast<u16x4*>(
                    vout + (size_t)nblk * 2048 + c * 8 + (lg & 1) * 4) = pw;
            }
        }
    }
}

// ---------------- K4: fused flash PV (r13 structure; intrinsic exp2) -------
__global__ __launch_bounds__(512) void k_attn_pv(const u16* __restrict__ qt,
        const u16* __restrict__ kt, const u16* __restrict__ vb,
        u16* __restrict__ yb) {
    int bid = blockIdx.x;
    int b = bid & 7, q0 = (bid >> 3) * 64;
    int t = threadIdx.x, w = t >> 6, l = t & 63, lg = l >> 4, lr = l & 15;
    int band = w & 3, mfb = w >> 2; // wave scores band `band`, mf in {mfb, mfb+2}
    __shared__ u16 Pl[16384];      // flat: [buf 8192][half 4096][n*64+m swizzled]
    __shared__ float Ls[2][64];

    const u16* Qt = qt + ((size_t)b * NPIX + q0) * 16;

    const bf16x8 zf = {0, 0, 0, 0, 0, 0, 0, 0};
    bf16x8 qf = zf;
    if (lg < 2)
        qf = *reinterpret_cast<const bf16x8*>(Qt + (band * 16 + lr) * 16 + lg * 8);

    // hoisted pointers (stepped per iteration)
    const u16* kp  = kt + (size_t)b * NPIX * 16 + (size_t)(mfb * 16 + lr) * 16 + lg * 8;
    // V tiled: elem(c, m) at (m>>3)*2048 + c*8 + (m&7); lane reads m = .. + lg*8
    const u16* vp0 = vb + (size_t)b * PD * NPIX + lg * 2048 + (size_t)(w * 32 + lr) * 8;
    const u16* vp1 = vp0 + 128; // +16 c

    float lp = 0.f;
    const f32x4 z4 = {0.f, 0.f, 0.f, 0.f};
    f32x4 acc[2][4];
#pragma unroll
    for (int cf = 0; cf < 2; ++cf)
#pragma unroll
        for (int nf = 0; nf < 4; ++nf) acc[cf][nf] = z4;

    int n = band * 16 + lr;
    int swz = (n & 7) << 3;
    int wrb = (n * 64 + mfb * 16 + 4 * lg) ^ swz; // f-variant: ^(i*32), +h*4096

    int bufo = 0;
    for (int it = 0; it < 32; ++it) {
        // ---- scores S^T = K·Q^T: 4 frags (2 halves x 2 mf) ----
#pragma unroll
        for (int f = 0; f < 4; ++f) {
            int h = f >> 1, i = f & 1;
            bf16x8 kf = zf;
            if (lg < 2)
                kf = *reinterpret_cast<const bf16x8*>(kp + h * 1024 + i * 512);
            f32x4 s = MFMA16(kf, qf, z4);
            float p0 = fexp2(s[0]);
            float p1 = fexp2(s[1]);
            float p2 = fexp2(s[2]);
            float p3 = fexp2(s[3]);
            lp += (p0 + p1) + (p2 + p3);
            uint2 pw;
            pw.x = cvtpk(p0, p1);
            pw.y = cvtpk(p2, p3);
            *reinterpret_cast<uint2*>(
                &Pl[bufo + h * 4096 + (wrb ^ (i * 32))]) = pw;
        }
        __syncthreads(); // P ready
        // ---- PV over 4 slices (h, ks): acc[c][n] += V[c][m] * P[n][m] ----
#pragma unroll
        for (int sl = 0; sl < 4; ++sl) {
            int h = sl >> 1, ks = sl & 1;
            bf16x8 vf0 = *reinterpret_cast<const bf16x8*>(
                vp0 + (h * 8 + ks * 4) * 2048);
            bf16x8 vf1 = *reinterpret_cast<const bf16x8*>(
                vp1 + (h * 8 + ks * 4) * 2048);
#pragma unroll
            for (int nf = 0; nf < 4; ++nf) {
                int nn = nf * 16 + lr;
                bf16x8 pf = *reinterpret_cast<const bf16x8*>(
                    &Pl[bufo + h * 4096 +
                        ((nn * 64 + ks * 32 + lg * 8) ^ ((nn & 7) << 3))]);
                acc[0][nf] = MFMA16(vf0, pf, acc[0][nf]);
                acc[1][nf] = MFMA16(vf1, pf, acc[1][nf]);
            }
        }
        kp += 2048; vp0 += 32768; vp1 += 32768;
        bufo ^= 8192;
    }
    // ---- finalize L: lane partial covers its (lg, mf-pair) m-slices ----
    lp += __shfl_xor(lp, 16);
    lp += __shfl_xor(lp, 32);
    if (l < 16) Ls[mfb][band * 16 + l] = lp; // waves mfb=0/1 hold complementary mf
    __syncthreads();
    float invl[4];
#pragma unroll
    for (int nf = 0; nf < 4; ++nf)
        invl[nf] = 1.f / (Ls[0][nf * 16 + lr] + Ls[1][nf * 16 + lr]);
    // ---- epilogue: /L, SiLU, write y TILED: (c>>3)*32768 + n*8 + (c&7) ----
    u16* ybase = yb + (size_t)b * NPIX * CDIM;
#pragma unroll
    for (int nf = 0; nf < 4; ++nf) {
        int nq = q0 + nf * 16 + lr;
#pragma unroll
        for (int cf = 0; cf < 2; ++cf) {
            int cg = w * 32 + cf * 16 + 4 * lg;
            u16x4 pw;
#pragma unroll
            for (int r = 0; r < 4; ++r) {
                float v = acc[cf][nf][r] * invl[nf];
                pw[r] = f2bf(v / (1.f + __expf(-v)));
            }
            *reinterpret_cast<u16x4*>(
                ybase + (size_t)(cg >> 3) * 32768 + nq * 8 + (cg & 7)) = pw;
        }
    }
}

// -------- K6: out = w_proj_bf16 @ y_bf16 + b_proj (MFMA, tiled reads) ------
__global__ __launch_bounds__(256) void k_proj_mfma(const u16* __restrict__ wb,
        const u16* __restrict__ yb, const float* __restrict__ bproj,
        float* __restrict__ out) {
    int b = blockIdx.z, n0 = blockIdx.x * 128, o0 = blockIdx.y * 128;
    int t = threadIdx.x, w = t >> 6, l = t & 63, lg = l >> 4, lr = l & 15;
    int wo = w & 1, wn = w >> 1;
    int obase = o0 + wo * 64, nbase = n0 + wn * 64;
    const u16* ybb = yb + (size_t)b * NPIX * CDIM;
    const f32x4 z4 = {0.f, 0.f, 0.f, 0.f};
    f32x4 acc[4][4];
#pragma unroll
    for (int i = 0; i < 4; ++i)
#pragma unroll
        for (int j = 0; j < 4; ++j) acc[i][j] = z4;

    for (int k0 = 0; k0 < CDIM; k0 += 32) {
        bf16x8 af[4], bfr[4];
#pragma unroll
        for (int of = 0; of < 4; ++of)
            af[of] = *reinterpret_cast<const bf16x8*>(
                wb + (size_t)((k0 >> 3) + lg) * 4096 + (obase + of * 16 + lr) * 8);
#pragma unroll
        for (int nf = 0; nf < 4; ++nf)
            bfr[nf] = *reinterpret_cast<const bf16x8*>(
                ybb + (size_t)((k0 >> 3) + lg) * 32768 + (nbase + nf * 16 + lr) * 8);
#pragma unroll
        for (int of = 0; of < 4; ++of)
#pragma unroll
            for (int nf = 0; nf < 4; ++nf)
                acc[of][nf] = MFMA16(af[of], bfr[nf], acc[of][nf]);
    }
#pragma unroll
    for (int of = 0; of < 4; ++of) {
        int o = obase + of * 16 + 4 * lg;
#pragma unroll
        for (int r = 0; r < 4; ++r) {
            float bb = bproj[o + r];
#pragma unroll
            for (int nf = 0; nf < 4; ++nf)
                out[((size_t)b * CDIM + o + r) * NPIX + nbase + nf * 16 + lr] =
                    acc[of][nf][r] + bb;
        }
    }
}

extern "C" void kernel_launch(void* const* d_in, const int* in_sizes, int n_in,
                              void* d_out, int out_size, void* d_ws, size_t ws_size,
                              hipStream_t stream) {
    const float* x     = (const float*)d_in[0];
    const float* gnw   = (const float*)d_in[1];
    const float* gnb   = (const float*)d_in[2];
    const float* wqkv  = (const float*)d_in[3];
    const float* bqkv  = (const float*)d_in[4];
    const float* wproj = (const float*)d_in[5];
    const float* bproj = (const float*)d_in[6];
    float* out = (float*)d_out;
    float* wsf = (float*)d_ws;

    u16* qtp = (u16*)d_ws + U16_BASE;
    u16* ktp = qtp + QT_ELEMS;
    u16* vbp = ktp + QT_ELEMS;
    u16* ybp = vbp + V_ELEMS;
    u16* wbp = ybp + Y_ELEMS;
    u16* wqb = wbp + WP_ELEMS;
    u16* xnp = wqb + WQ_ELEMS;

    k_stats_partial<<<dim3(64, 8), 256, 0, stream>>>(x, wsf);
    k_stats_final<<<8, 64, 0, stream>>>(wsf);
    k_cvt2<<<328, 256, 0, stream>>>(wproj, wqkv, wbp, wqb);
    k_prep<<<dim3(64, 8, 8), 256, 0, stream>>>(x, gnw, gnb, wsf, xnp, ybp);
    k_qkv<<<dim3(16, 9, 8), 256, 0, stream>>>(xnp, wqb, bqkv, qtp, ktp, vbp);
    k_attn_pv<<<512, 512, 0, stream>>>(qtp, ktp, vbp, ybp);
    k_proj_mfma<<<dim3(32, 4, 8), 256, 0, stream>>>(wbp, ybp, bproj, out);
}